// Round 7
// baseline (254.294 us; speedup 1.0000x reference)
//
#include <hip/hip_runtime.h>
#include <math.h>

#define B_N 32768
#define L_N 128
#define M_N 1024
#define NT 512
#define TB 64
#define TM 64
#define NCHUNK (M_N / TM)

typedef __bf16 v8bf __attribute__((ext_vector_type(8)));
typedef float  v4f  __attribute__((ext_vector_type(4)));

#define MFMA(a, b, c) __builtin_amdgcn_mfma_f32_16x16x32_bf16(a, b, c, 0, 0, 0)

// element strides
#define US  136   // u_bf [64][136] bf16
#define CNS 136   // c_n  [64][136] bf16
#define CTS 72    // c_t  [128][72] bf16 (padded, no swizzle)
#define CFS 66    // cfl  [64 m][66 b] fp32
#define TMS 132   // T_m  [64 b][132 l] fp32 (post-loop, overlaps c_t+cfl)

// byte offsets into dynamic LDS
#define OFF_UBF   0
#define OFF_CN    17408
#define OFF_CT    34816
#define OFF_TM_   34816   // T_m: 64*132*4 = 33792 -> ends 68608 (< OFF_USQ)
#define OFF_CFL   53248
#define OFF_USQ   70144
#define OFF_UPART 70400
#define OFF_SRED  72704
#define OFF_RRED  73856
#define OFF_G     75008
#define OFF_RS    75264
#define SMEM_BYTES 75520

#define AMP 64.0f

__device__ inline v8bf pack8(float4 a, float4 b) {
    v8bf v;
    v[0] = (__bf16)a.x; v[1] = (__bf16)a.y; v[2] = (__bf16)a.z; v[3] = (__bf16)a.w;
    v[4] = (__bf16)b.x; v[5] = (__bf16)b.y; v[6] = (__bf16)b.z; v[7] = (__bf16)b.w;
    return v;
}

__global__ void lebnn_precompute(const float* __restrict__ centres,
                                 const float* __restrict__ log_sigmas,
                                 const float* __restrict__ lin_w,
                                 float4* __restrict__ cpack) {
    int m = blockIdx.x * blockDim.x + threadIdx.x;
    if (m >= M_N) return;
    const float4* row = (const float4*)(centres + (size_t)m * L_N);
    float s = 0.f;
#pragma unroll
    for (int i = 0; i < L_N / 4; ++i) {
        float4 v = row[i];
        s += v.x * v.x + v.y * v.y + v.z * v.z + v.w * v.w;
    }
    float4 p;
    p.x = s;
    p.y = expf(-2.f * log_sigmas[m]);   // 1/sigma^2
    p.z = lin_w[m];
    p.w = 0.f;
    cpack[m] = p;
}

__global__ __launch_bounds__(NT) void lebnn_fused(
    const float* __restrict__ u, const float* __restrict__ centres,
    const float4* __restrict__ cpack, float* __restrict__ out)
{
    extern __shared__ char smem[];
    __bf16* u_bf = (__bf16*)(smem + OFF_UBF);
    __bf16* c_n  = (__bf16*)(smem + OFF_CN);
    __bf16* c_t  = (__bf16*)(smem + OFF_CT);
    float*  cfl  = (float*)(smem + OFF_CFL);
    float*  T_m  = (float*)(smem + OFF_TM_);
    float* usq_s = (float*)(smem + OFF_USQ);
    float* upart = (float*)(smem + OFF_UPART);
    float* sred  = (float*)(smem + OFF_SRED);
    float* rred  = (float*)(smem + OFF_RRED);
    float* gsh   = (float*)(smem + OFF_G);
    float* rssh  = (float*)(smem + OFF_RS);

    const int tid  = threadIdx.x;
    const int w    = tid >> 6;
    const int lane = tid & 63;
    const int l15  = lane & 15;
    const int l4   = lane >> 4;
    const int bh   = w >> 2;        // b-half
    const int mq   = w & 3;         // GEMM1 m-quarter
    const int lq   = w & 3;         // GEMM2 l-quarter
    const int tx   = tid & 15;      // VALU-T / final epilogue: b-group of 4
    const int ty   = tid >> 4;      // VALU-T / final epilogue: l-group of 4 (0..31)
    const int b0   = blockIdx.x * TB;

    // ---------------- stage u (fp32 -> bf16) + row sumsq ----------------
    {
        int row = tid >> 3, seg = tid & 7;
        const float* up = u + (size_t)(b0 + row) * L_N + seg * 16;
        float4 a0 = *(const float4*)(up);
        float4 a1 = *(const float4*)(up + 4);
        float4 a2 = *(const float4*)(up + 8);
        float4 a3 = *(const float4*)(up + 12);
        float ps = a0.x*a0.x + a0.y*a0.y + a0.z*a0.z + a0.w*a0.w
                 + a1.x*a1.x + a1.y*a1.y + a1.z*a1.z + a1.w*a1.w
                 + a2.x*a2.x + a2.y*a2.y + a2.z*a2.z + a2.w*a2.w
                 + a3.x*a3.x + a3.y*a3.y + a3.z*a3.z + a3.w*a3.w;
        *(v8bf*)&u_bf[row * US + seg * 16]     = pack8(a0, a1);
        *(v8bf*)&u_bf[row * US + seg * 16 + 8] = pack8(a2, a3);
        upart[row * 9 + seg] = ps;
    }
    __syncthreads();
    if (tid < TB) {
        float s = 0.f;
#pragma unroll
        for (int i = 0; i < 8; ++i) s += upart[tid * 9 + i];
        usq_s[tid] = s;
    }
    __syncthreads();

    // ---------------- preload u fragments + usq regs ----------------
    v8bf uf[2][4];
#pragma unroll
    for (int bt = 0; bt < 2; ++bt)
#pragma unroll
        for (int kk = 0; kk < 4; ++kk)
            uf[bt][kk] = *(v8bf*)&u_bf[(bh*32 + bt*16 + l15) * US + kk*32 + l4*8];

    float usq_r[2][4];
#pragma unroll
    for (int bt = 0; bt < 2; ++bt)
#pragma unroll
        for (int r = 0; r < 4; ++r)
            usq_r[bt][r] = usq_s[bh*32 + bt*16 + l4*4 + r];

    v4f Tacc[2][2];
#pragma unroll
    for (int bt = 0; bt < 2; ++bt)
#pragma unroll
        for (int lt = 0; lt < 2; ++lt)
            Tacc[bt][lt] = (v4f){0.f, 0.f, 0.f, 0.f};

    float s_p[2][4] = {{0.f,0.f,0.f,0.f},{0.f,0.f,0.f,0.f}};
    float r_p[2][4] = {{0.f,0.f,0.f,0.f},{0.f,0.f,0.f,0.f}};
    float Tv[4][4] = {{0.f}};   // r3-verified VALU T, tx/ty layout

    const int rp = tid >> 4;   // staging row-pair 0..31
    const int cg = tid & 15;   // staging col-group

    // ---------------- main loop over m-chunks ----------------
    for (int mt = 0; mt < NCHUNK; ++mt) {
        const int m0 = mt * TM;
        __syncthreads();   // A
        {
            const float* cp0 = centres + (size_t)(m0 + 2*rp) * L_N + cg * 8;
            float4 r0a = *(const float4*)(cp0);
            float4 r0b = *(const float4*)(cp0 + 4);
            float4 r1a = *(const float4*)(cp0 + L_N);
            float4 r1b = *(const float4*)(cp0 + L_N + 4);
            *(v8bf*)&c_n[(2*rp)     * CNS + cg*8] = pack8(r0a, r0b);
            *(v8bf*)&c_n[(2*rp + 1) * CNS + cg*8] = pack8(r1a, r1b);
        }
        float4 cpv = cpack[m0 + mq*16 + l15];
        __syncthreads();   // B

        // GEMM1 (MFMA, verified)
        v4f dot[2];
        dot[0] = (v4f){0.f,0.f,0.f,0.f};
        dot[1] = (v4f){0.f,0.f,0.f,0.f};
#pragma unroll
        for (int kk = 0; kk < 4; ++kk) {
            v8bf bfr = *(v8bf*)&c_n[(mq*16 + l15) * CNS + kk*32 + l4*8];
            dot[0] = MFMA(uf[0][kk], bfr, dot[0]);
            dot[1] = MFMA(uf[1][kk], bfr, dot[1]);
        }

        // elementwise -> cfl[m][b] fp32 (verified store pattern)
#pragma unroll
        for (int bt = 0; bt < 2; ++bt) {
#pragma unroll
            for (int r = 0; r < 4; ++r) {
                float dv  = dot[bt][r];
                float raw = fmaf(-2.f, dv, usq_r[bt][r] + cpv.x);
                float x   = fmaf(fmaxf(raw, 0.f), cpv.y, 1.f);
                float ri  = rsqrtf(x);
                s_p[bt][r] = fmaf(cpv.z, x * ri, s_p[bt][r]);
                float qv  = (raw > 0.f) ? cpv.z * cpv.y * ri : 0.f;
                r_p[bt][r] += qv;
                cfl[(mq*16 + l15) * CFS + bh*32 + bt*16 + l4*4 + r] = qv;
            }
        }

        // build c_t [128 l][64 m] from c_n
        {
            int lrow = tid >> 2;
            int mg   = tid & 3;
            v8bf t0, t1;
#pragma unroll
            for (int i = 0; i < 8; ++i) t0[i] = c_n[(mg*16 + i) * CNS + lrow];
#pragma unroll
            for (int i = 0; i < 8; ++i) t1[i] = c_n[(mg*16 + 8 + i) * CNS + lrow];
            *(v8bf*)&c_t[lrow * CTS + mg*16]     = t0;
            *(v8bf*)&c_t[lrow * CTS + mg*16 + 8] = t1;
        }
        __syncthreads();   // C

        // GEMM2 (MFMA under test): A gathered from cfl (bf16-rounded)
#pragma unroll
        for (int kk = 0; kk < 2; ++kk) {
            v8bf qa0, qa1;
#pragma unroll
            for (int p = 0; p < 8; ++p) {
                int mrow = (kk*32 + l4*8 + p) * CFS;
                qa0[p] = (__bf16)cfl[mrow + bh*32 +  0 + l15];
                qa1[p] = (__bf16)cfl[mrow + bh*32 + 16 + l15];
            }
#pragma unroll
            for (int lt = 0; lt < 2; ++lt) {
                v8bf cb = *(v8bf*)&c_t[(lq*32 + lt*16 + l15) * CTS + kk*32 + l4*8];
                Tacc[0][lt] = MFMA(qa0, cb, Tacc[0][lt]);
                Tacc[1][lt] = MFMA(qa1, cb, Tacc[1][lt]);
            }
        }

        // GEMM2 (VALU reference, r3-verified semantics, same bf16 operands)
        for (int mm = 0; mm < TM; ++mm) {
            float cf[4], cv[4];
#pragma unroll
            for (int i = 0; i < 4; ++i) cf[i] = (float)(__bf16)cfl[mm * CFS + tx*4 + i];
#pragma unroll
            for (int j = 0; j < 4; ++j) cv[j] = (float)c_n[mm * CNS + ty*4 + j];
#pragma unroll
            for (int i = 0; i < 4; ++i)
#pragma unroll
                for (int j = 0; j < 4; ++j)
                    Tv[i][j] = fmaf(cf[i], cv[j], Tv[i][j]);
        }
    }

    __syncthreads();   // D

    // dump MFMA T to LDS via fragment addressing (under test)
#pragma unroll
    for (int bt = 0; bt < 2; ++bt)
#pragma unroll
        for (int lt = 0; lt < 2; ++lt)
#pragma unroll
            for (int r = 0; r < 4; ++r)
                T_m[(bh*32 + bt*16 + l4*4 + r) * TMS + lq*32 + lt*16 + l15] =
                    Tacc[bt][lt][r];

    // reduce s, R over the 16-lane m-groups (verified)
#pragma unroll
    for (int bt = 0; bt < 2; ++bt)
#pragma unroll
        for (int r = 0; r < 4; ++r) {
#pragma unroll
            for (int msk = 1; msk < 16; msk <<= 1) {
                s_p[bt][r] += __shfl_xor(s_p[bt][r], msk, 64);
                r_p[bt][r] += __shfl_xor(r_p[bt][r], msk, 64);
            }
        }
    if (l15 == 0) {
#pragma unroll
        for (int bt = 0; bt < 2; ++bt)
#pragma unroll
            for (int r = 0; r < 4; ++r) {
                sred[w*36 + bt*16 + l4*4 + r] = s_p[bt][r];
                rred[w*36 + bt*16 + l4*4 + r] = r_p[bt][r];
            }
    }
    __syncthreads();   // E

    if (tid < TB) {
        int bhh = tid >> 5, rowr = tid & 31;
        float s = 0.f, R = 0.f;
#pragma unroll
        for (int i = 0; i < 4; ++i) {
            s += sred[(bhh*4 + i)*36 + rowr];
            R += rred[(bhh*4 + i)*36 + rowr];
        }
        float g = (s > 0.f) ? 1.f : expf(s);
        gsh[tid]  = g;
        rssh[tid] = fmaf(g, R, 1.f);
    }
    __syncthreads();   // F

    // ---------------- final epilogue: r3-verified tx/ty write + diff probe ---
#pragma unroll
    for (int i = 0; i < 4; ++i) {
        int b = tx*4 + i;
        float rv2 = rssh[b];
        float gv2 = gsh[b];
#pragma unroll
        for (int j = 0; j < 4; ++j) {
            int l = ty*4 + j;
            size_t idx = (size_t)(b0 + b) * L_N + l;
            float diff = T_m[b * TMS + l] - Tv[i][j];
            out[idx] = fmaf(u[idx], rv2, -gv2 * Tv[i][j]) + AMP * diff;
        }
    }
}

extern "C" void kernel_launch(void* const* d_in, const int* in_sizes, int n_in,
                              void* d_out, int out_size, void* d_ws, size_t ws_size,
                              hipStream_t stream) {
    const float* u          = (const float*)d_in[0];
    const float* centres    = (const float*)d_in[1];
    const float* log_sigmas = (const float*)d_in[2];
    const float* lin_w      = (const float*)d_in[3];
    float* out = (float*)d_out;
    float4* cpack = (float4*)d_ws;   // 16 KB

    lebnn_precompute<<<(M_N + 255) / 256, 256, 0, stream>>>(centres, log_sigmas, lin_w, cpack);

    hipFuncSetAttribute((const void*)lebnn_fused,
                        hipFuncAttributeMaxDynamicSharedMemorySize, SMEM_BYTES);
    lebnn_fused<<<B_N / TB, NT, SMEM_BYTES, stream>>>(u, centres, cpack, out);
}

// Round 9
// 77.231 us; speedup vs baseline: 3.2927x; 3.2927x over previous
//
#include <hip/hip_runtime.h>
#include <math.h>

#define B_N 32768
#define L_N 128
#define M_N 1024
#define NT 512
#define TB 64
#define TM 64
#define NCHUNK (M_N / TM)

typedef __bf16 v8bf __attribute__((ext_vector_type(8)));
typedef __bf16 v4bf __attribute__((ext_vector_type(4)));
typedef float  v4f  __attribute__((ext_vector_type(4)));

#define MFMA(a, b, c) __builtin_amdgcn_mfma_f32_16x16x32_bf16(a, b, c, 0, 0, 0)

#define US  136   // u_bf [64][136] bf16
#define CNS 136   // c_n  [64][136] bf16

__device__ inline v8bf pack8(float4 a, float4 b) {
    v8bf v;
    v[0] = (__bf16)a.x; v[1] = (__bf16)a.y; v[2] = (__bf16)a.z; v[3] = (__bf16)a.w;
    v[4] = (__bf16)b.x; v[5] = (__bf16)b.y; v[6] = (__bf16)b.z; v[7] = (__bf16)b.w;
    return v;
}

// ---------------- shared precompute: c_sq, 1/sigma^2, w ----------------
__global__ void lebnn_precompute(const float* __restrict__ centres,
                                 const float* __restrict__ log_sigmas,
                                 const float* __restrict__ lin_w,
                                 float4* __restrict__ cpack) {
    int m = blockIdx.x * blockDim.x + threadIdx.x;
    if (m >= M_N) return;
    const float4* row = (const float4*)(centres + (size_t)m * L_N);
    float s = 0.f;
#pragma unroll
    for (int i = 0; i < L_N / 4; ++i) {
        float4 v = row[i];
        s += v.x * v.x + v.y * v.y + v.z * v.z + v.w * v.w;
    }
    float4 p;
    p.x = s;
    p.y = expf(-2.f * log_sigmas[m]);
    p.z = lin_w[m];
    p.w = 0.f;
    cpack[m] = p;
}

// ---------------- transpose: centres [1024][128] fp32 -> cT [128][1024] bf16
__global__ void lebnn_transpose(const float* __restrict__ centres,
                                __bf16* __restrict__ cT) {
    __shared__ __bf16 tile[64 * 72];
    const int m0 = blockIdx.x * 64;
    const int l0 = blockIdx.y * 64;
    const int row = threadIdx.x >> 2;   // 0..63
    const int seg = threadIdx.x & 3;    // 16 elems each
    const float* src = centres + (size_t)(m0 + row) * L_N + l0 + seg * 16;
    float4 a0 = *(const float4*)(src);
    float4 a1 = *(const float4*)(src + 4);
    float4 a2 = *(const float4*)(src + 8);
    float4 a3 = *(const float4*)(src + 12);
    *(v8bf*)&tile[row * 72 + seg * 16]     = pack8(a0, a1);
    *(v8bf*)&tile[row * 72 + seg * 16 + 8] = pack8(a2, a3);
    __syncthreads();
    v8bf o0, o1;
#pragma unroll
    for (int i = 0; i < 8; ++i) o0[i] = tile[(seg * 16 + i) * 72 + row];
#pragma unroll
    for (int i = 0; i < 8; ++i) o1[i] = tile[(seg * 16 + 8 + i) * 72 + row];
    __bf16* dst = cT + (size_t)(l0 + row) * M_N + m0 + seg * 16;
    *(v8bf*)(dst)     = o0;
    *(v8bf*)(dst + 8) = o1;
}

// ---------------- Kernel A: GEMM1 + elementwise -> q (global), g, rs --------
__global__ __launch_bounds__(NT) void lebnn_phase1(
    const float* __restrict__ u, const float* __restrict__ centres,
    const float4* __restrict__ cpack, __bf16* __restrict__ qg,
    float* __restrict__ gg, float* __restrict__ rsg)
{
    __shared__ __bf16 u_bf[64 * US];
    __shared__ __bf16 c_n[64 * CNS];
    __shared__ float usq_s[64];
    __shared__ float upart[64 * 9];
    __shared__ float sred[288];
    __shared__ float rred[288];

    const int tid  = threadIdx.x;
    const int w    = tid >> 6;
    const int lane = tid & 63;
    const int l15  = lane & 15;
    const int l4   = lane >> 4;
    const int bh   = w >> 2;
    const int mq   = w & 3;
    const int b0   = blockIdx.x * TB;

    // stage u (fp32 -> bf16) + row sumsq  (r3-verified)
    {
        int row = tid >> 3, seg = tid & 7;
        const float* up = u + (size_t)(b0 + row) * L_N + seg * 16;
        float4 a0 = *(const float4*)(up);
        float4 a1 = *(const float4*)(up + 4);
        float4 a2 = *(const float4*)(up + 8);
        float4 a3 = *(const float4*)(up + 12);
        float ps = a0.x*a0.x + a0.y*a0.y + a0.z*a0.z + a0.w*a0.w
                 + a1.x*a1.x + a1.y*a1.y + a1.z*a1.z + a1.w*a1.w
                 + a2.x*a2.x + a2.y*a2.y + a2.z*a2.z + a2.w*a2.w
                 + a3.x*a3.x + a3.y*a3.y + a3.z*a3.z + a3.w*a3.w;
        *(v8bf*)&u_bf[row * US + seg * 16]     = pack8(a0, a1);
        *(v8bf*)&u_bf[row * US + seg * 16 + 8] = pack8(a2, a3);
        upart[row * 9 + seg] = ps;
    }
    __syncthreads();
    if (tid < TB) {
        float s = 0.f;
#pragma unroll
        for (int i = 0; i < 8; ++i) s += upart[tid * 9 + i];
        usq_s[tid] = s;
    }
    __syncthreads();

    v8bf uf[2][4];
#pragma unroll
    for (int bt = 0; bt < 2; ++bt)
#pragma unroll
        for (int kk = 0; kk < 4; ++kk)
            uf[bt][kk] = *(v8bf*)&u_bf[(bh*32 + bt*16 + l15) * US + kk*32 + l4*8];

    float usq_r[2][4];
#pragma unroll
    for (int bt = 0; bt < 2; ++bt)
#pragma unroll
        for (int r = 0; r < 4; ++r)
            usq_r[bt][r] = usq_s[bh*32 + bt*16 + l4*4 + r];

    float s_p[2][4] = {{0.f,0.f,0.f,0.f},{0.f,0.f,0.f,0.f}};
    float r_p[2][4] = {{0.f,0.f,0.f,0.f},{0.f,0.f,0.f,0.f}};

    const int rp = tid >> 4;
    const int cg = tid & 15;

    for (int mt = 0; mt < NCHUNK; ++mt) {
        const int m0 = mt * TM;
        __syncthreads();   // A: prev GEMM1 c_n reads done
        {
            const float* cp0 = centres + (size_t)(m0 + 2*rp) * L_N + cg * 8;
            float4 r0a = *(const float4*)(cp0);
            float4 r0b = *(const float4*)(cp0 + 4);
            float4 r1a = *(const float4*)(cp0 + L_N);
            float4 r1b = *(const float4*)(cp0 + L_N + 4);
            *(v8bf*)&c_n[(2*rp)     * CNS + cg*8] = pack8(r0a, r0b);
            *(v8bf*)&c_n[(2*rp + 1) * CNS + cg*8] = pack8(r1a, r1b);
        }
        float4 cpv = cpack[m0 + mq*16 + l15];
        __syncthreads();   // B: c_n staged

        v4f dot[2];
        dot[0] = (v4f){0.f,0.f,0.f,0.f};
        dot[1] = (v4f){0.f,0.f,0.f,0.f};
#pragma unroll
        for (int kk = 0; kk < 4; ++kk) {
            v8bf bfr = *(v8bf*)&c_n[(mq*16 + l15) * CNS + kk*32 + l4*8];
            dot[0] = MFMA(uf[0][kk], bfr, dot[0]);
            dot[1] = MFMA(uf[1][kk], bfr, dot[1]);
        }

#pragma unroll
        for (int bt = 0; bt < 2; ++bt) {
#pragma unroll
            for (int r = 0; r < 4; ++r) {
                float dv  = dot[bt][r];
                float raw = fmaf(-2.f, dv, usq_r[bt][r] + cpv.x);
                float x   = fmaf(fmaxf(raw, 0.f), cpv.y, 1.f);
                float ri  = rsqrtf(x);
                s_p[bt][r] = fmaf(cpv.z, x * ri, s_p[bt][r]);
                float qv  = (raw > 0.f) ? cpv.z * cpv.y * ri : 0.f;
                r_p[bt][r] += qv;
                qg[(size_t)(b0 + bh*32 + bt*16 + l4*4 + r) * M_N + m0 + mq*16 + l15]
                    = (__bf16)qv;
            }
        }
    }

    // reduce s, R (r3-verified)
#pragma unroll
    for (int bt = 0; bt < 2; ++bt)
#pragma unroll
        for (int r = 0; r < 4; ++r) {
#pragma unroll
            for (int msk = 1; msk < 16; msk <<= 1) {
                s_p[bt][r] += __shfl_xor(s_p[bt][r], msk, 64);
                r_p[bt][r] += __shfl_xor(r_p[bt][r], msk, 64);
            }
        }
    if (l15 == 0) {
#pragma unroll
        for (int bt = 0; bt < 2; ++bt)
#pragma unroll
            for (int r = 0; r < 4; ++r) {
                sred[w*36 + bt*16 + l4*4 + r] = s_p[bt][r];
                rred[w*36 + bt*16 + l4*4 + r] = r_p[bt][r];
            }
    }
    __syncthreads();

    if (tid < TB) {
        int bhh = tid >> 5, rowr = tid & 31;
        float s = 0.f, R = 0.f;
#pragma unroll
        for (int i = 0; i < 4; ++i) {
            s += sred[(bhh*4 + i)*36 + rowr];
            R += rred[(bhh*4 + i)*36 + rowr];
        }
        float g = (s > 0.f) ? 1.f : expf(s);
        gg[b0 + tid]  = g;
        rsg[b0 + tid] = fmaf(g, R, 1.f);
    }
}

// ---------------- Kernel B: T[b][l] = sum_m q[b][m] * cT[l][m]  (m92 pattern)
__global__ __launch_bounds__(NT) void lebnn_gemm2(
    const __bf16* __restrict__ qg, const __bf16* __restrict__ cT,
    float* __restrict__ Tg)
{
    __shared__ __bf16 qt[64 * 72];
    __shared__ __bf16 ct[128 * 72];

    const int tid  = threadIdx.x;
    const int w    = tid >> 6;
    const int lane = tid & 63;
    const int l15  = lane & 15;
    const int l4   = lane >> 4;
    const int bh   = w >> 2;        // b-half
    const int lq   = w & 3;         // l-quarter
    const int bb0  = blockIdx.x * 64;

    v4f acc[2][2];
#pragma unroll
    for (int bt = 0; bt < 2; ++bt)
#pragma unroll
        for (int lt = 0; lt < 2; ++lt)
            acc[bt][lt] = (v4f){0.f, 0.f, 0.f, 0.f};

    for (int mt = 0; mt < NCHUNK; ++mt) {
        const int m0 = mt * TM;
        __syncthreads();
        {
            int row = tid >> 3, seg = tid & 7;   // q tile [64 b][64 m]
            *(v8bf*)&qt[row * 72 + seg * 8] =
                *(const v8bf*)(qg + (size_t)(bb0 + row) * M_N + m0 + seg * 8);
        }
        {
            int lr = tid >> 2, sg = tid & 3;     // ct tile [128 l][64 m]
            const __bf16* src = cT + (size_t)lr * M_N + m0 + sg * 16;
            *(v8bf*)&ct[lr * 72 + sg * 16]     = *(const v8bf*)(src);
            *(v8bf*)&ct[lr * 72 + sg * 16 + 8] = *(const v8bf*)(src + 8);
        }
        __syncthreads();

#pragma unroll
        for (int kk = 0; kk < 2; ++kk) {
            v8bf qa0 = *(v8bf*)&qt[(bh*32 +  0 + l15) * 72 + kk*32 + l4*8];
            v8bf qa1 = *(v8bf*)&qt[(bh*32 + 16 + l15) * 72 + kk*32 + l4*8];
#pragma unroll
            for (int lt = 0; lt < 2; ++lt) {
                v8bf cb = *(v8bf*)&ct[(lq*32 + lt*16 + l15) * 72 + kk*32 + l4*8];
                acc[0][lt] = MFMA(qa0, cb, acc[0][lt]);
                acc[1][lt] = MFMA(qa1, cb, acc[1][lt]);
            }
        }
    }

#pragma unroll
    for (int bt = 0; bt < 2; ++bt)
#pragma unroll
        for (int lt = 0; lt < 2; ++lt)
#pragma unroll
            for (int r = 0; r < 4; ++r)
                Tg[(size_t)(bb0 + bh*32 + bt*16 + l4*4 + r) * L_N
                   + lq*32 + lt*16 + l15] = acc[bt][lt][r];
}

// ---------------- Kernel C: out = u*rs - g*T ----------------
__global__ __launch_bounds__(256) void lebnn_epilogue(
    const float* __restrict__ u, const float* __restrict__ Tg,
    const float* __restrict__ gg, const float* __restrict__ rsg,
    float* __restrict__ out)
{
    int i = blockIdx.x * 256 + threadIdx.x;   // float4 index, exact grid
    int b = i >> 5;
    float4 uu = ((const float4*)u)[i];
    float4 tt = ((const float4*)Tg)[i];
    float g = gg[b], rs = rsg[b];
    float4 o;
    o.x = fmaf(uu.x, rs, -g * tt.x);
    o.y = fmaf(uu.y, rs, -g * tt.y);
    o.z = fmaf(uu.z, rs, -g * tt.z);
    o.w = fmaf(uu.w, rs, -g * tt.w);
    ((float4*)out)[i] = o;
}

// ================= FALLBACK: round-3 kernel, verbatim =================
#define CFS 68
#define OFF_UBF   0
#define OFF_CN    17408
#define OFF_CFL   34816
#define OFF_USQ   52224
#define OFF_UPART 52480
#define OFF_SRED  54784
#define OFF_RRED  55936
#define OFF_G     57088
#define OFF_RS    57344
#define SMEM_BYTES 57600

__global__ __launch_bounds__(NT) void lebnn_fallback(
    const float* __restrict__ u, const float* __restrict__ centres,
    const float4* __restrict__ cpack, float* __restrict__ out)
{
    extern __shared__ char smem[];
    __bf16* u_bf = (__bf16*)(smem + OFF_UBF);
    __bf16* c_n  = (__bf16*)(smem + OFF_CN);
    float*  cfl  = (float*)(smem + OFF_CFL);
    float* usq_s = (float*)(smem + OFF_USQ);
    float* upart = (float*)(smem + OFF_UPART);
    float* sred  = (float*)(smem + OFF_SRED);
    float* rred  = (float*)(smem + OFF_RRED);
    float* gsh   = (float*)(smem + OFF_G);
    float* rssh  = (float*)(smem + OFF_RS);

    const int tid  = threadIdx.x;
    const int w    = tid >> 6;
    const int lane = tid & 63;
    const int l15  = lane & 15;
    const int l4   = lane >> 4;
    const int bh   = w >> 2;
    const int mq   = w & 3;
    const int tx   = tid & 15;
    const int ty   = tid >> 4;
    const int b0   = blockIdx.x * TB;

    {
        int row = tid >> 3, seg = tid & 7;
        const float* up = u + (size_t)(b0 + row) * L_N + seg * 16;
        float4 a0 = *(const float4*)(up);
        float4 a1 = *(const float4*)(up + 4);
        float4 a2 = *(const float4*)(up + 8);
        float4 a3 = *(const float4*)(up + 12);
        float ps = a0.x*a0.x + a0.y*a0.y + a0.z*a0.z + a0.w*a0.w
                 + a1.x*a1.x + a1.y*a1.y + a1.z*a1.z + a1.w*a1.w
                 + a2.x*a2.x + a2.y*a2.y + a2.z*a2.z + a2.w*a2.w
                 + a3.x*a3.x + a3.y*a3.y + a3.z*a3.z + a3.w*a3.w;
        *(v8bf*)&u_bf[row * US + seg * 16]     = pack8(a0, a1);
        *(v8bf*)&u_bf[row * US + seg * 16 + 8] = pack8(a2, a3);
        upart[row * 9 + seg] = ps;
    }
    __syncthreads();
    if (tid < TB) {
        float s = 0.f;
#pragma unroll
        for (int i = 0; i < 8; ++i) s += upart[tid * 9 + i];
        usq_s[tid] = s;
    }
    __syncthreads();

    v8bf uf[2][4];
#pragma unroll
    for (int bt = 0; bt < 2; ++bt)
#pragma unroll
        for (int kk = 0; kk < 4; ++kk)
            uf[bt][kk] = *(v8bf*)&u_bf[(bh*32 + bt*16 + l15) * US + kk*32 + l4*8];

    float usq_r[2][4];
#pragma unroll
    for (int bt = 0; bt < 2; ++bt)
#pragma unroll
        for (int r = 0; r < 4; ++r)
            usq_r[bt][r] = usq_s[bh*32 + bt*16 + l4*4 + r];

    float s_p[2][4] = {{0.f,0.f,0.f,0.f},{0.f,0.f,0.f,0.f}};
    float r_p[2][4] = {{0.f,0.f,0.f,0.f},{0.f,0.f,0.f,0.f}};
    float T[4][4] = {{0.f}};

    const int rp = tid >> 4;
    const int cg = tid & 15;

    for (int mt = 0; mt < NCHUNK; ++mt) {
        const int m0 = mt * TM;
        __syncthreads();
        {
            const float* cp0 = centres + (size_t)(m0 + 2*rp) * L_N + cg * 8;
            float4 r0a = *(const float4*)(cp0);
            float4 r0b = *(const float4*)(cp0 + 4);
            float4 r1a = *(const float4*)(cp0 + L_N);
            float4 r1b = *(const float4*)(cp0 + L_N + 4);
            *(v8bf*)&c_n[(2*rp)     * CNS + cg*8] = pack8(r0a, r0b);
            *(v8bf*)&c_n[(2*rp + 1) * CNS + cg*8] = pack8(r1a, r1b);
        }
        float4 cpv = cpack[m0 + mq*16 + l15];
        __syncthreads();

        v4f dot[2];
        dot[0] = (v4f){0.f,0.f,0.f,0.f};
        dot[1] = (v4f){0.f,0.f,0.f,0.f};
#pragma unroll
        for (int kk = 0; kk < 4; ++kk) {
            v8bf bfr = *(v8bf*)&c_n[(mq*16 + l15) * CNS + kk*32 + l4*8];
            dot[0] = MFMA(uf[0][kk], bfr, dot[0]);
            dot[1] = MFMA(uf[1][kk], bfr, dot[1]);
        }

#pragma unroll
        for (int bt = 0; bt < 2; ++bt) {
#pragma unroll
            for (int r = 0; r < 4; ++r) {
                float dv  = dot[bt][r];
                float raw = fmaf(-2.f, dv, usq_r[bt][r] + cpv.x);
                float x   = fmaf(fmaxf(raw, 0.f), cpv.y, 1.f);
                float ri  = rsqrtf(x);
                s_p[bt][r] = fmaf(cpv.z, x * ri, s_p[bt][r]);
                float qv  = (raw > 0.f) ? cpv.z * cpv.y * ri : 0.f;
                r_p[bt][r] += qv;
                cfl[(mq*16 + l15) * CFS + bh*32 + bt*16 + l4*4 + r] = qv;
            }
        }
        __syncthreads();

        for (int mm = 0; mm < TM; ++mm) {
            v4f cf = *(v4f*)&cfl[mm * CFS + tx*4];
            v4bf cb = *(v4bf*)&c_n[mm * CNS + ty*4];
            float cv[4] = {(float)cb[0], (float)cb[1], (float)cb[2], (float)cb[3]};
#pragma unroll
            for (int i = 0; i < 4; ++i)
#pragma unroll
                for (int j = 0; j < 4; ++j)
                    T[i][j] = fmaf(cf[i], cv[j], T[i][j]);
        }
    }

    __syncthreads();

#pragma unroll
    for (int bt = 0; bt < 2; ++bt)
#pragma unroll
        for (int r = 0; r < 4; ++r) {
#pragma unroll
            for (int msk = 1; msk < 16; msk <<= 1) {
                s_p[bt][r] += __shfl_xor(s_p[bt][r], msk, 64);
                r_p[bt][r] += __shfl_xor(r_p[bt][r], msk, 64);
            }
        }
    if (l15 == 0) {
#pragma unroll
        for (int bt = 0; bt < 2; ++bt)
#pragma unroll
            for (int r = 0; r < 4; ++r) {
                sred[w*36 + bt*16 + l4*4 + r] = s_p[bt][r];
                rred[w*36 + bt*16 + l4*4 + r] = r_p[bt][r];
            }
    }
    __syncthreads();

    if (tid < TB) {
        int bhh = tid >> 5, rowr = tid & 31;
        float s = 0.f, R = 0.f;
#pragma unroll
        for (int i = 0; i < 4; ++i) {
            s += sred[(bhh*4 + i)*36 + rowr];
            R += rred[(bhh*4 + i)*36 + rowr];
        }
        float g = (s > 0.f) ? 1.f : expf(s);
        gsh[tid]  = g;
        rssh[tid] = fmaf(g, R, 1.f);
    }
    __syncthreads();

#pragma unroll
    for (int i = 0; i < 4; ++i) {
        int b = tx*4 + i;
        float rv = rssh[b];
        float gv = gsh[b];
        size_t idx = (size_t)(b0 + b) * L_N + ty*4;
        float4 uu = *(const float4*)(u + idx);
        float4 o;
        o.x = fmaf(uu.x, rv, -gv * T[i][0]);
        o.y = fmaf(uu.y, rv, -gv * T[i][1]);
        o.z = fmaf(uu.z, rv, -gv * T[i][2]);
        o.w = fmaf(uu.w, rv, -gv * T[i][3]);
        *(float4*)(out + idx) = o;
    }
}

extern "C" void kernel_launch(void* const* d_in, const int* in_sizes, int n_in,
                              void* d_out, int out_size, void* d_ws, size_t ws_size,
                              hipStream_t stream) {
    const float* u          = (const float*)d_in[0];
    const float* centres    = (const float*)d_in[1];
    const float* log_sigmas = (const float*)d_in[2];
    const float* lin_w      = (const float*)d_in[3];
    float* out = (float*)d_out;

    char* wsb = (char*)d_ws;
    float4* cpack = (float4*)wsb;                        //      16384 B
    __bf16* cT    = (__bf16*)(wsb + 16384);              //     262144 B
    float*  gg    = (float*) (wsb + 278528);             //     131072 B
    float*  rsg   = (float*) (wsb + 409600);             //     131072 B
    __bf16* qg    = (__bf16*)(wsb + 540672);             //   67108864 B
    float*  Tg    = out;   // T is consumed by epilogue before out overwrite? NO:
    // Tg must not alias out (epilogue reads Tg and writes out at same idx in
    // one thread — aliasing would still be correct elementwise, but keep them
    // separate if ws allows; we need 16 MB more:
    const size_t WS_NEED = 540672ULL + 67108864ULL + 16777216ULL;
    Tg = (float*)(wsb + 540672 + 67108864);              //   16777216 B

    lebnn_precompute<<<(M_N + 255) / 256, 256, 0, stream>>>(centres, log_sigmas, lin_w, cpack);

    if (ws_size >= WS_NEED) {
        lebnn_transpose<<<dim3(M_N / 64, L_N / 64), 256, 0, stream>>>(centres, cT);
        lebnn_phase1<<<B_N / TB, NT, 0, stream>>>(u, centres, cpack, qg, gg, rsg);
        lebnn_gemm2<<<B_N / 64, NT, 0, stream>>>(qg, cT, Tg);
        lebnn_epilogue<<<(B_N * L_N / 4) / 256, 256, 0, stream>>>(u, Tg, gg, rsg, out);
    } else {
        hipFuncSetAttribute((const void*)lebnn_fallback,
                            hipFuncAttributeMaxDynamicSharedMemorySize, SMEM_BYTES);
        lebnn_fallback<<<B_N / TB, NT, SMEM_BYTES, stream>>>(u, centres, cpack, out);
    }
}

// Round 10
// 73.073 us; speedup vs baseline: 3.4800x; 1.0569x over previous
//
#include <hip/hip_runtime.h>
#include <math.h>

#define B_N 32768
#define L_N 128
#define M_N 1024
#define NT 512
#define TB 64
#define TM 64
#define NCHUNK (M_N / TM)

typedef __bf16 v8bf __attribute__((ext_vector_type(8)));
typedef __bf16 v4bf __attribute__((ext_vector_type(4)));
typedef float  v4f  __attribute__((ext_vector_type(4)));

#define MFMA(a, b, c) __builtin_amdgcn_mfma_f32_16x16x32_bf16(a, b, c, 0, 0, 0)

#define US  136   // u_bf [64][136] bf16
#define CNS 136   // c_n  [64][136] bf16

__device__ inline v8bf pack8(float4 a, float4 b) {
    v8bf v;
    v[0] = (__bf16)a.x; v[1] = (__bf16)a.y; v[2] = (__bf16)a.z; v[3] = (__bf16)a.w;
    v[4] = (__bf16)b.x; v[5] = (__bf16)b.y; v[6] = (__bf16)b.z; v[7] = (__bf16)b.w;
    return v;
}

// ---------------- shared precompute: c_sq, 1/sigma^2, w ----------------
__global__ void lebnn_precompute(const float* __restrict__ centres,
                                 const float* __restrict__ log_sigmas,
                                 const float* __restrict__ lin_w,
                                 float4* __restrict__ cpack) {
    int m = blockIdx.x * blockDim.x + threadIdx.x;
    if (m >= M_N) return;
    const float4* row = (const float4*)(centres + (size_t)m * L_N);
    float s = 0.f;
#pragma unroll
    for (int i = 0; i < L_N / 4; ++i) {
        float4 v = row[i];
        s += v.x * v.x + v.y * v.y + v.z * v.z + v.w * v.w;
    }
    float4 p;
    p.x = s;
    p.y = expf(-2.f * log_sigmas[m]);
    p.z = lin_w[m];
    p.w = 0.f;
    cpack[m] = p;
}

// ---------------- transpose: centres [1024][128] fp32 -> cT [128][1024] bf16
__global__ void lebnn_transpose(const float* __restrict__ centres,
                                __bf16* __restrict__ cT) {
    __shared__ __bf16 tile[64 * 72];
    const int m0 = blockIdx.x * 64;
    const int l0 = blockIdx.y * 64;
    const int row = threadIdx.x >> 2;   // 0..63
    const int seg = threadIdx.x & 3;    // 16 elems each
    const float* src = centres + (size_t)(m0 + row) * L_N + l0 + seg * 16;
    float4 a0 = *(const float4*)(src);
    float4 a1 = *(const float4*)(src + 4);
    float4 a2 = *(const float4*)(src + 8);
    float4 a3 = *(const float4*)(src + 12);
    *(v8bf*)&tile[row * 72 + seg * 16]     = pack8(a0, a1);
    *(v8bf*)&tile[row * 72 + seg * 16 + 8] = pack8(a2, a3);
    __syncthreads();
    v8bf o0, o1;
#pragma unroll
    for (int i = 0; i < 8; ++i) o0[i] = tile[(seg * 16 + i) * 72 + row];
#pragma unroll
    for (int i = 0; i < 8; ++i) o1[i] = tile[(seg * 16 + 8 + i) * 72 + row];
    __bf16* dst = cT + (size_t)(l0 + row) * M_N + m0 + seg * 16;
    *(v8bf*)(dst)     = o0;
    *(v8bf*)(dst + 8) = o1;
}

// ---------------- Kernel A: GEMM1 + elementwise -> q (packed chunks), g, rs -
// q global layout: qg[blk][mt][tid][8] — thread tid's 8 values (bt*4+r) for
// chunk mt of block blk. 16B/thread/chunk, fully coalesced.
__global__ __launch_bounds__(NT) void lebnn_phase1(
    const float* __restrict__ u, const float* __restrict__ centres,
    const float4* __restrict__ cpack, __bf16* __restrict__ qg,
    float* __restrict__ gg, float* __restrict__ rsg)
{
    __shared__ __bf16 u_bf[64 * US];
    __shared__ __bf16 c_n[64 * CNS];
    __shared__ float usq_s[64];
    __shared__ float upart[64 * 9];
    __shared__ float sred[288];
    __shared__ float rred[288];

    const int tid  = threadIdx.x;
    const int w    = tid >> 6;
    const int lane = tid & 63;
    const int l15  = lane & 15;
    const int l4   = lane >> 4;
    const int bh   = w >> 2;
    const int mq   = w & 3;
    const int b0   = blockIdx.x * TB;

    // stage u (fp32 -> bf16) + row sumsq  (r3-verified)
    {
        int row = tid >> 3, seg = tid & 7;
        const float* up = u + (size_t)(b0 + row) * L_N + seg * 16;
        float4 a0 = *(const float4*)(up);
        float4 a1 = *(const float4*)(up + 4);
        float4 a2 = *(const float4*)(up + 8);
        float4 a3 = *(const float4*)(up + 12);
        float ps = a0.x*a0.x + a0.y*a0.y + a0.z*a0.z + a0.w*a0.w
                 + a1.x*a1.x + a1.y*a1.y + a1.z*a1.z + a1.w*a1.w
                 + a2.x*a2.x + a2.y*a2.y + a2.z*a2.z + a2.w*a2.w
                 + a3.x*a3.x + a3.y*a3.y + a3.z*a3.z + a3.w*a3.w;
        *(v8bf*)&u_bf[row * US + seg * 16]     = pack8(a0, a1);
        *(v8bf*)&u_bf[row * US + seg * 16 + 8] = pack8(a2, a3);
        upart[row * 9 + seg] = ps;
    }
    __syncthreads();
    if (tid < TB) {
        float s = 0.f;
#pragma unroll
        for (int i = 0; i < 8; ++i) s += upart[tid * 9 + i];
        usq_s[tid] = s;
    }
    __syncthreads();

    v8bf uf[2][4];
#pragma unroll
    for (int bt = 0; bt < 2; ++bt)
#pragma unroll
        for (int kk = 0; kk < 4; ++kk)
            uf[bt][kk] = *(v8bf*)&u_bf[(bh*32 + bt*16 + l15) * US + kk*32 + l4*8];

    float usq_r[2][4];
#pragma unroll
    for (int bt = 0; bt < 2; ++bt)
#pragma unroll
        for (int r = 0; r < 4; ++r)
            usq_r[bt][r] = usq_s[bh*32 + bt*16 + l4*4 + r];

    float s_p[2][4] = {{0.f,0.f,0.f,0.f},{0.f,0.f,0.f,0.f}};
    float r_p[2][4] = {{0.f,0.f,0.f,0.f},{0.f,0.f,0.f,0.f}};

    const int rp = tid >> 4;
    const int cg = tid & 15;

    for (int mt = 0; mt < NCHUNK; ++mt) {
        const int m0 = mt * TM;
        __syncthreads();   // A: prev GEMM1 c_n reads done
        {
            const float* cp0 = centres + (size_t)(m0 + 2*rp) * L_N + cg * 8;
            float4 r0a = *(const float4*)(cp0);
            float4 r0b = *(const float4*)(cp0 + 4);
            float4 r1a = *(const float4*)(cp0 + L_N);
            float4 r1b = *(const float4*)(cp0 + L_N + 4);
            *(v8bf*)&c_n[(2*rp)     * CNS + cg*8] = pack8(r0a, r0b);
            *(v8bf*)&c_n[(2*rp + 1) * CNS + cg*8] = pack8(r1a, r1b);
        }
        float4 cpv = cpack[m0 + mq*16 + l15];
        __syncthreads();   // B: c_n staged

        v4f dot[2];
        dot[0] = (v4f){0.f,0.f,0.f,0.f};
        dot[1] = (v4f){0.f,0.f,0.f,0.f};
#pragma unroll
        for (int kk = 0; kk < 4; ++kk) {
            v8bf bfr = *(v8bf*)&c_n[(mq*16 + l15) * CNS + kk*32 + l4*8];
            dot[0] = MFMA(uf[0][kk], bfr, dot[0]);
            dot[1] = MFMA(uf[1][kk], bfr, dot[1]);
        }

        v8bf qv8;
        const float wq = cpv.z * cpv.y;
#pragma unroll
        for (int bt = 0; bt < 2; ++bt) {
#pragma unroll
            for (int r = 0; r < 4; ++r) {
                float dv  = dot[bt][r];
                float raw = fmaf(-2.f, dv, usq_r[bt][r] + cpv.x);
                float x   = fmaf(fmaxf(raw, 0.f), cpv.y, 1.f);
                float ri  = rsqrtf(x);
                s_p[bt][r] = fmaf(cpv.z, x * ri, s_p[bt][r]);
                float qv  = (raw > 0.f) ? wq * ri : 0.f;
                r_p[bt][r] += qv;
                qv8[bt*4 + r] = (__bf16)qv;
            }
        }
        // one coalesced 16B store per thread per chunk
        *(v8bf*)(qg + ((size_t)blockIdx.x * NCHUNK + mt) * (NT * 8) + tid * 8) = qv8;
    }

    // reduce s, R (r3-verified)
#pragma unroll
    for (int bt = 0; bt < 2; ++bt)
#pragma unroll
        for (int r = 0; r < 4; ++r) {
#pragma unroll
            for (int msk = 1; msk < 16; msk <<= 1) {
                s_p[bt][r] += __shfl_xor(s_p[bt][r], msk, 64);
                r_p[bt][r] += __shfl_xor(r_p[bt][r], msk, 64);
            }
        }
    if (l15 == 0) {
#pragma unroll
        for (int bt = 0; bt < 2; ++bt)
#pragma unroll
            for (int r = 0; r < 4; ++r) {
                sred[w*36 + bt*16 + l4*4 + r] = s_p[bt][r];
                rred[w*36 + bt*16 + l4*4 + r] = r_p[bt][r];
            }
    }
    __syncthreads();

    if (tid < TB) {
        int bhh = tid >> 5, rowr = tid & 31;
        float s = 0.f, R = 0.f;
#pragma unroll
        for (int i = 0; i < 4; ++i) {
            s += sred[(bhh*4 + i)*36 + rowr];
            R += rred[(bhh*4 + i)*36 + rowr];
        }
        float g = (s > 0.f) ? 1.f : expf(s);
        gg[b0 + tid]  = g;
        rsg[b0 + tid] = fmaf(g, R, 1.f);
    }
}

// ---------------- Kernel B: T = q @ C, fused epilogue out = u*rs - g*T ------
__global__ __launch_bounds__(NT) void lebnn_gemm2(
    const float* __restrict__ u, const __bf16* __restrict__ qg,
    const __bf16* __restrict__ cT, const float* __restrict__ gg,
    const float* __restrict__ rsg, float* __restrict__ out)
{
    __shared__ __bf16 qt[64 * 72];
    __shared__ __bf16 ct[128 * 72];

    const int tid  = threadIdx.x;
    const int w    = tid >> 6;
    const int lane = tid & 63;
    const int l15  = lane & 15;
    const int l4   = lane >> 4;
    const int bh   = w >> 2;        // b-half (also phase1's packing bh)
    const int lq   = w & 3;         // l-quarter (also phase1's packing mq)
    const int bb0  = blockIdx.x * 64;

    v4f acc[2][2];
#pragma unroll
    for (int bt = 0; bt < 2; ++bt)
#pragma unroll
        for (int lt = 0; lt < 2; ++lt)
            acc[bt][lt] = (v4f){0.f, 0.f, 0.f, 0.f};

    for (int mt = 0; mt < NCHUNK; ++mt) {
        const int m0 = mt * TM;
        __syncthreads();
        {
            // unpack this thread's 16B of q (same tid->(b,m) map as phase1)
            v8bf qv = *(const v8bf*)(qg + ((size_t)blockIdx.x * NCHUNK + mt) * (NT * 8) + tid * 8);
#pragma unroll
            for (int bt = 0; bt < 2; ++bt)
#pragma unroll
                for (int r = 0; r < 4; ++r)
                    qt[(bh*32 + bt*16 + l4*4 + r) * 72 + lq*16 + l15] = qv[bt*4 + r];
        }
        {
            int lr = tid >> 2, sg = tid & 3;     // ct tile [128 l][64 m]
            const __bf16* src = cT + (size_t)lr * M_N + m0 + sg * 16;
            *(v8bf*)&ct[lr * 72 + sg * 16]     = *(const v8bf*)(src);
            *(v8bf*)&ct[lr * 72 + sg * 16 + 8] = *(const v8bf*)(src + 8);
        }
        __syncthreads();

#pragma unroll
        for (int kk = 0; kk < 2; ++kk) {
            v8bf qa0 = *(v8bf*)&qt[(bh*32 +  0 + l15) * 72 + kk*32 + l4*8];
            v8bf qa1 = *(v8bf*)&qt[(bh*32 + 16 + l15) * 72 + kk*32 + l4*8];
#pragma unroll
            for (int lt = 0; lt < 2; ++lt) {
                v8bf cb = *(v8bf*)&ct[(lq*32 + lt*16 + l15) * 72 + kk*32 + l4*8];
                acc[0][lt] = MFMA(qa0, cb, acc[0][lt]);
                acc[1][lt] = MFMA(qa1, cb, acc[1][lt]);
            }
        }
    }

    // fused epilogue: store indices identical to r9's verified Tg store
    float gv[2][4], rv[2][4];
#pragma unroll
    for (int bt = 0; bt < 2; ++bt)
#pragma unroll
        for (int r = 0; r < 4; ++r) {
            int b = bb0 + bh*32 + bt*16 + l4*4 + r;
            gv[bt][r] = gg[b];
            rv[bt][r] = rsg[b];
        }
#pragma unroll
    for (int bt = 0; bt < 2; ++bt)
#pragma unroll
        for (int lt = 0; lt < 2; ++lt)
#pragma unroll
            for (int r = 0; r < 4; ++r) {
                size_t idx = (size_t)(bb0 + bh*32 + bt*16 + l4*4 + r) * L_N
                           + lq*32 + lt*16 + l15;
                out[idx] = fmaf(u[idx], rv[bt][r], -gv[bt][r] * acc[bt][lt][r]);
            }
}

// ================= FALLBACK: round-3 kernel, verbatim =================
#define CFS 68
#define OFF_UBF   0
#define OFF_CN    17408
#define OFF_CFL   34816
#define OFF_USQ   52224
#define OFF_UPART 52480
#define OFF_SRED  54784
#define OFF_RRED  55936
#define OFF_G     57088
#define OFF_RS    57344
#define SMEM_BYTES 57600

__global__ __launch_bounds__(NT) void lebnn_fallback(
    const float* __restrict__ u, const float* __restrict__ centres,
    const float4* __restrict__ cpack, float* __restrict__ out)
{
    extern __shared__ char smem[];
    __bf16* u_bf = (__bf16*)(smem + OFF_UBF);
    __bf16* c_n  = (__bf16*)(smem + OFF_CN);
    float*  cfl  = (float*)(smem + OFF_CFL);
    float* usq_s = (float*)(smem + OFF_USQ);
    float* upart = (float*)(smem + OFF_UPART);
    float* sred  = (float*)(smem + OFF_SRED);
    float* rred  = (float*)(smem + OFF_RRED);
    float* gsh   = (float*)(smem + OFF_G);
    float* rssh  = (float*)(smem + OFF_RS);

    const int tid  = threadIdx.x;
    const int w    = tid >> 6;
    const int lane = tid & 63;
    const int l15  = lane & 15;
    const int l4   = lane >> 4;
    const int bh   = w >> 2;
    const int mq   = w & 3;
    const int tx   = tid & 15;
    const int ty   = tid >> 4;
    const int b0   = blockIdx.x * TB;

    {
        int row = tid >> 3, seg = tid & 7;
        const float* up = u + (size_t)(b0 + row) * L_N + seg * 16;
        float4 a0 = *(const float4*)(up);
        float4 a1 = *(const float4*)(up + 4);
        float4 a2 = *(const float4*)(up + 8);
        float4 a3 = *(const float4*)(up + 12);
        float ps = a0.x*a0.x + a0.y*a0.y + a0.z*a0.z + a0.w*a0.w
                 + a1.x*a1.x + a1.y*a1.y + a1.z*a1.z + a1.w*a1.w
                 + a2.x*a2.x + a2.y*a2.y + a2.z*a2.z + a2.w*a2.w
                 + a3.x*a3.x + a3.y*a3.y + a3.z*a3.z + a3.w*a3.w;
        *(v8bf*)&u_bf[row * US + seg * 16]     = pack8(a0, a1);
        *(v8bf*)&u_bf[row * US + seg * 16 + 8] = pack8(a2, a3);
        upart[row * 9 + seg] = ps;
    }
    __syncthreads();
    if (tid < TB) {
        float s = 0.f;
#pragma unroll
        for (int i = 0; i < 8; ++i) s += upart[tid * 9 + i];
        usq_s[tid] = s;
    }
    __syncthreads();

    v8bf uf[2][4];
#pragma unroll
    for (int bt = 0; bt < 2; ++bt)
#pragma unroll
        for (int kk = 0; kk < 4; ++kk)
            uf[bt][kk] = *(v8bf*)&u_bf[(bh*32 + bt*16 + l15) * US + kk*32 + l4*8];

    float usq_r[2][4];
#pragma unroll
    for (int bt = 0; bt < 2; ++bt)
#pragma unroll
        for (int r = 0; r < 4; ++r)
            usq_r[bt][r] = usq_s[bh*32 + bt*16 + l4*4 + r];

    float s_p[2][4] = {{0.f,0.f,0.f,0.f},{0.f,0.f,0.f,0.f}};
    float r_p[2][4] = {{0.f,0.f,0.f,0.f},{0.f,0.f,0.f,0.f}};
    float T[4][4] = {{0.f}};

    const int rp = tid >> 4;
    const int cg = tid & 15;

    for (int mt = 0; mt < NCHUNK; ++mt) {
        const int m0 = mt * TM;
        __syncthreads();
        {
            const float* cp0 = centres + (size_t)(m0 + 2*rp) * L_N + cg * 8;
            float4 r0a = *(const float4*)(cp0);
            float4 r0b = *(const float4*)(cp0 + 4);
            float4 r1a = *(const float4*)(cp0 + L_N);
            float4 r1b = *(const float4*)(cp0 + L_N + 4);
            *(v8bf*)&c_n[(2*rp)     * CNS + cg*8] = pack8(r0a, r0b);
            *(v8bf*)&c_n[(2*rp + 1) * CNS + cg*8] = pack8(r1a, r1b);
        }
        float4 cpv = cpack[m0 + mq*16 + l15];
        __syncthreads();

        v4f dot[2];
        dot[0] = (v4f){0.f,0.f,0.f,0.f};
        dot[1] = (v4f){0.f,0.f,0.f,0.f};
#pragma unroll
        for (int kk = 0; kk < 4; ++kk) {
            v8bf bfr = *(v8bf*)&c_n[(mq*16 + l15) * CNS + kk*32 + l4*8];
            dot[0] = MFMA(uf[0][kk], bfr, dot[0]);
            dot[1] = MFMA(uf[1][kk], bfr, dot[1]);
        }

#pragma unroll
        for (int bt = 0; bt < 2; ++bt) {
#pragma unroll
            for (int r = 0; r < 4; ++r) {
                float dv  = dot[bt][r];
                float raw = fmaf(-2.f, dv, usq_r[bt][r] + cpv.x);
                float x   = fmaf(fmaxf(raw, 0.f), cpv.y, 1.f);
                float ri  = rsqrtf(x);
                s_p[bt][r] = fmaf(cpv.z, x * ri, s_p[bt][r]);
                float qv  = (raw > 0.f) ? cpv.z * cpv.y * ri : 0.f;
                r_p[bt][r] += qv;
                cfl[(mq*16 + l15) * CFS + bh*32 + bt*16 + l4*4 + r] = qv;
            }
        }
        __syncthreads();

        for (int mm = 0; mm < TM; ++mm) {
            v4f cf = *(v4f*)&cfl[mm * CFS + tx*4];
            v4bf cb = *(v4bf*)&c_n[mm * CNS + ty*4];
            float cv[4] = {(float)cb[0], (float)cb[1], (float)cb[2], (float)cb[3]};
#pragma unroll
            for (int i = 0; i < 4; ++i)
#pragma unroll
                for (int j = 0; j < 4; ++j)
                    T[i][j] = fmaf(cf[i], cv[j], T[i][j]);
        }
    }

    __syncthreads();

#pragma unroll
    for (int bt = 0; bt < 2; ++bt)
#pragma unroll
        for (int r = 0; r < 4; ++r) {
#pragma unroll
            for (int msk = 1; msk < 16; msk <<= 1) {
                s_p[bt][r] += __shfl_xor(s_p[bt][r], msk, 64);
                r_p[bt][r] += __shfl_xor(r_p[bt][r], msk, 64);
            }
        }
    if (l15 == 0) {
#pragma unroll
        for (int bt = 0; bt < 2; ++bt)
#pragma unroll
            for (int r = 0; r < 4; ++r) {
                sred[w*36 + bt*16 + l4*4 + r] = s_p[bt][r];
                rred[w*36 + bt*16 + l4*4 + r] = r_p[bt][r];
            }
    }
    __syncthreads();

    if (tid < TB) {
        int bhh = tid >> 5, rowr = tid & 31;
        float s = 0.f, R = 0.f;
#pragma unroll
        for (int i = 0; i < 4; ++i) {
            s += sred[(bhh*4 + i)*36 + rowr];
            R += rred[(bhh*4 + i)*36 + rowr];
        }
        float g = (s > 0.f) ? 1.f : expf(s);
        gsh[tid]  = g;
        rssh[tid] = fmaf(g, R, 1.f);
    }
    __syncthreads();

#pragma unroll
    for (int i = 0; i < 4; ++i) {
        int b = tx*4 + i;
        float rv = rssh[b];
        float gv = gsh[b];
        size_t idx = (size_t)(b0 + b) * L_N + ty*4;
        float4 uu = *(const float4*)(u + idx);
        float4 o;
        o.x = fmaf(uu.x, rv, -gv * T[i][0]);
        o.y = fmaf(uu.y, rv, -gv * T[i][1]);
        o.z = fmaf(uu.z, rv, -gv * T[i][2]);
        o.w = fmaf(uu.w, rv, -gv * T[i][3]);
        *(float4*)(out + idx) = o;
    }
}

extern "C" void kernel_launch(void* const* d_in, const int* in_sizes, int n_in,
                              void* d_out, int out_size, void* d_ws, size_t ws_size,
                              hipStream_t stream) {
    const float* u          = (const float*)d_in[0];
    const float* centres    = (const float*)d_in[1];
    const float* log_sigmas = (const float*)d_in[2];
    const float* lin_w      = (const float*)d_in[3];
    float* out = (float*)d_out;

    char* wsb = (char*)d_ws;
    float4* cpack = (float4*)wsb;                        //      16384 B
    __bf16* cT    = (__bf16*)(wsb + 16384);              //     262144 B
    float*  gg    = (float*) (wsb + 278528);             //     131072 B
    float*  rsg   = (float*) (wsb + 409600);             //     131072 B
    __bf16* qg    = (__bf16*)(wsb + 540672);             //   67108864 B
    const size_t WS_NEED = 540672ULL + 67108864ULL;

    lebnn_precompute<<<(M_N + 255) / 256, 256, 0, stream>>>(centres, log_sigmas, lin_w, cpack);

    if (ws_size >= WS_NEED) {
        lebnn_transpose<<<dim3(M_N / 64, L_N / 64), 256, 0, stream>>>(centres, cT);
        lebnn_phase1<<<B_N / TB, NT, 0, stream>>>(u, centres, cpack, qg, gg, rsg);
        lebnn_gemm2<<<B_N / 64, NT, 0, stream>>>(u, qg, cT, gg, rsg, out);
    } else {
        hipFuncSetAttribute((const void*)lebnn_fallback,
                            hipFuncAttributeMaxDynamicSharedMemorySize, SMEM_BYTES);
        lebnn_fallback<<<B_N / TB, NT, SMEM_BYTES, stream>>>(u, centres, cpack, out);
    }
}